// Round 1
// baseline (7139.178 us; speedup 1.0000x reference)
//
#include <hip/hip_runtime.h>
#include <hip/hip_bf16.h>
#include <math.h>

#define N_PTS   131072
#define M_CENT  2048
#define K_GRP   32
#define NSTEP   2047          // num_samples - 1
#define NROWS   (M_CENT * K_GRP)   // 65536
#define NCHUNK  512           // chunks of 256 points
#define BN_EPS  1e-5f

// ---------------- FPS persistent kernel ----------------
#define FPS_NB 16
#define FPS_NT 256
#define FPS_PPT (N_PTS / (FPS_NB * FPS_NT))   // 32
#define FPS_NW (FPS_NT / 64)                  // 4 waves

__device__ __forceinline__ void triple_max(unsigned long long& b, float& x, float& y,
                                           unsigned long long ob, float ox, float oy) {
  if (ob > b) { b = ob; x = ox; y = oy; }
}

// Packed candidate: [dist_bits:32 | tag:15 | (131071-idx):17]
//  - dist >= 0 so float bits are monotone as uint
//  - tag = step+1 (1..2047); 0xAA poison decodes tag 21845 -> never matches
//  - inverted idx: max-reduce prefers LOWEST point index on exact dist ties (matches jnp.argmax)
__global__ __launch_bounds__(FPS_NT)
void fps_kernel(const float* __restrict__ pts, float* __restrict__ cents,
                float* __restrict__ outc,
                unsigned long long* __restrict__ slotA,
                unsigned long long* __restrict__ slotB) {
  const int b = blockIdx.x, t = threadIdx.x;
  const int lane = t & 63, wid = t >> 6;
  float px[FPS_PPT], py[FPS_PPT], dist[FPS_PPT];
  const int gbase = b * FPS_NT + t;
#pragma unroll
  for (int k = 0; k < FPS_PPT; k++) {
    int g = gbase + k * (FPS_NB * FPS_NT);
    px[k] = pts[2 * g]; py[k] = pts[2 * g + 1];
    dist[k] = __builtin_inff();
  }
  float cx = pts[0], cy = pts[1];
  if (b == 0 && t == 0) { cents[0] = cx; cents[1] = cy; outc[0] = cx; outc[1] = cy; }
  __shared__ unsigned long long lred[FPS_NW];
  __shared__ float lrx[FPS_NW], lry[FPS_NW];
  __shared__ float s_cx, s_cy;

  for (int s = 0; s < NSTEP; s++) {
    const unsigned tag = (unsigned)(s + 1);
    unsigned long long best = 0ull; float bx = 0.f, by = 0.f;
#pragma unroll
    for (int k = 0; k < FPS_PPT; k++) {
      // exactly match reference: nd = sqrt(dx*dx + dy*dy), no fma contraction
      float dx = __fsub_rn(px[k], cx), dy = __fsub_rn(py[k], cy);
      float d2 = __fadd_rn(__fmul_rn(dx, dx), __fmul_rn(dy, dy));
      float nd = __fsqrt_rn(d2);              // correctly-rounded sqrt
      float dm = fminf(dist[k], nd);
      dist[k] = dm;
      unsigned long long p = ((unsigned long long)__float_as_uint(dm) << 32)
                           | ((unsigned long long)tag << 17)
                           | (unsigned)(N_PTS - 1 - (gbase + k * (FPS_NB * FPS_NT)));
      if (p > best) { best = p; bx = px[k]; by = py[k]; }
    }
    // wave reduce (carry coords with the max)
#pragma unroll
    for (int off = 32; off > 0; off >>= 1) {
      unsigned long long ob = __shfl_down(best, off);
      float ox = __shfl_down(bx, off), oy = __shfl_down(by, off);
      triple_max(best, bx, by, ob, ox, oy);
    }
    if (lane == 0) { lred[wid] = best; lrx[wid] = bx; lry[wid] = by; }
    __syncthreads();
    if (wid == 0) {
      if (lane < FPS_NW) { best = lred[lane]; bx = lrx[lane]; by = lry[lane]; }
      else { best = 0ull; bx = 0.f; by = 0.f; }
#pragma unroll
      for (int off = FPS_NW / 2; off > 0; off >>= 1) {
        unsigned long long ob = __shfl_down(best, off);
        float ox = __shfl_down(bx, off), oy = __shfl_down(by, off);
        triple_max(best, bx, by, ob, ox, oy);
      }
      // double-buffered slots by step parity: overwrite of step-s value only at
      // step s+2, by which time every block has consumed step s (proof: a block
      // reaches s+2 only after seeing all s+1 writes, each of which happens
      // after that writer consumed all step-s slots).
      unsigned long long* sA = slotA + (s & 1) * FPS_NB;
      unsigned long long* sB = slotB + (s & 1) * FPS_NB;
      if (lane == 0) {
        unsigned long long coords = ((unsigned long long)__float_as_uint(by) << 32)
                                  | (unsigned long long)__float_as_uint(bx);
        __hip_atomic_store(&sB[b], coords, __ATOMIC_RELAXED, __HIP_MEMORY_SCOPE_AGENT);
        __hip_atomic_store(&sA[b], best,  __ATOMIC_RELEASE, __HIP_MEMORY_SCOPE_AGENT);
      }
      unsigned long long gb = 0ull; float gx = 0.f, gy = 0.f;
      if (lane < FPS_NB) {
        unsigned long long v;
        do {
          v = __hip_atomic_load(&sA[lane], __ATOMIC_ACQUIRE, __HIP_MEMORY_SCOPE_AGENT);
        } while (((v >> 17) & 0x7FFFull) != (unsigned long long)tag);
        unsigned long long c = __hip_atomic_load(&sB[lane], __ATOMIC_RELAXED, __HIP_MEMORY_SCOPE_AGENT);
        gb = v; gx = __uint_as_float((unsigned)c); gy = __uint_as_float((unsigned)(c >> 32));
      }
#pragma unroll
      for (int off = FPS_NB / 2; off > 0; off >>= 1) {
        unsigned long long ob = __shfl_down(gb, off);
        float ox = __shfl_down(gx, off), oy = __shfl_down(gy, off);
        triple_max(gb, gx, gy, ob, ox, oy);
      }
      if (lane == 0) {
        s_cx = gx; s_cy = gy;
        if (b == 0) {
          cents[2 * (s + 1)] = gx; cents[2 * (s + 1) + 1] = gy;
          outc[2 * (s + 1)] = gx;  outc[2 * (s + 1) + 1] = gy;
        }
      }
    }
    __syncthreads();
    cx = s_cx; cy = s_cy;
  }
}

// ---------------- nearest-centroid assignment ----------------
__global__ __launch_bounds__(256)
void assign_kernel(const float* __restrict__ pts, const float* __restrict__ cents,
                   int* __restrict__ assign) {
  __shared__ float scx[M_CENT], scy[M_CENT], sc2[M_CENT];
  const int t = threadIdx.x;
  for (int i = t; i < M_CENT; i += 256) {
    float x = cents[2 * i], y = cents[2 * i + 1];
    scx[i] = x; scy[i] = y;
    sc2[i] = __fadd_rn(__fmul_rn(x, x), __fmul_rn(y, y));
  }
  __syncthreads();
  const int n = blockIdx.x * 256 + t;
  float x = pts[2 * n], y = pts[2 * n + 1];
  float p2 = __fadd_rn(__fmul_rn(x, x), __fmul_rn(y, y));
  float best = __builtin_inff(); int bm = 0;
  for (int m = 0; m < M_CENT; m++) {
    // reference formula: (p2 + c2) - 2*(p.c), no fma
    float dot = __fadd_rn(__fmul_rn(x, scx[m]), __fmul_rn(y, scy[m]));
    float d2 = __fsub_rn(__fadd_rn(p2, sc2[m]), __fmul_rn(2.0f, dot));
    if (d2 < best) { best = d2; bm = m; }   // strict < : first-min tie-break
  }
  assign[n] = bm;
}

// ---------------- chunk histogram + intra-chunk stable rank ----------------
__global__ __launch_bounds__(256)
void hist_kernel(const int* __restrict__ assign, unsigned* __restrict__ gcounts,
                 unsigned char* __restrict__ ranks) {
  __shared__ unsigned hist[M_CENT];
  __shared__ int sa[256];
  const int t = threadIdx.x, c = blockIdx.x;
  for (int i = t; i < M_CENT; i += 256) hist[i] = 0u;
  __syncthreads();
  const int n = c * 256 + t;
  const int m = assign[n];
  sa[t] = m;
  atomicAdd(&hist[m], 1u);
  __syncthreads();
  int r = 0;
  for (int j = 0; j < t; j++) r += (sa[j] == m);   // broadcast LDS reads
  ranks[n] = (unsigned char)r;
  for (int i = t; i < M_CENT; i += 256) gcounts[(size_t)c * M_CENT + i] = hist[i];
}

// ---------------- per-centroid exclusive scan over chunks ----------------
__global__ __launch_bounds__(256)
void scan_kernel(unsigned* __restrict__ gcounts, unsigned* __restrict__ counts) {
  const int m = blockIdx.x * 256 + threadIdx.x;   // 8 blocks -> 2048 centroids
  unsigned run = 0;
  for (int ch = 0; ch < NCHUNK; ch++) {
    unsigned v = gcounts[(size_t)ch * M_CENT + m];
    gcounts[(size_t)ch * M_CENT + m] = run;
    run += v;
  }
  counts[m] = run;
}

// ---------------- scatter first-32 (lowest-index) per centroid ----------------
__global__ __launch_bounds__(256)
void scatter_kernel(const int* __restrict__ assign, const unsigned char* __restrict__ ranks,
                    const unsigned* __restrict__ gexcl, int* __restrict__ sel) {
  const int n = blockIdx.x * 256 + threadIdx.x;
  const int m = assign[n];
  unsigned pos = gexcl[(size_t)blockIdx.x * M_CENT + m] + (unsigned)ranks[n];
  if (pos < K_GRP) sel[m * K_GRP + pos] = n;
}

// ---------------- gather + HF encoding ----------------
__global__ __launch_bounds__(256)
void encode_kernel(const float* __restrict__ pts, const float* __restrict__ cents,
                   const int* __restrict__ sel, const unsigned* __restrict__ counts,
                   float* __restrict__ enc) {
  const int tid = blockIdx.x * 256 + threadIdx.x;   // 0..65535
  const int m = tid >> 5, k = tid & 31;
  const unsigned cnt = counts[m];
  const float cx = cents[2 * m], cy = cents[2 * m + 1];
  float rx, ry;
  if (cnt == 0u) {
    if (k == 0) { rx = 0.f; ry = 0.f; }             // slot0 = centroid -> rel 0
    else        { rx = 0.f - cx; ry = 0.f - cy; }   // others grouped=0 -> rel=-c
  } else {
    int kk = ((unsigned)k < cnt) ? k : (int)cnt - 1;  // pad with last assigned
    int n = sel[m * K_GRP + kk];
    rx = __fsub_rn(pts[2 * n], cx);
    ry = __fsub_rn(pts[2 * n + 1], cy);
  }
  float row[40];
  float fr = 3.14159265358979323846f;   // rounds to float(pi); doubling is exact
#pragma unroll
  for (int f = 0; f < 10; f++) {
    float ax = __fmul_rn(rx, fr), ay = __fmul_rn(ry, fr);
    float sx, cxs, sy, cys;
    sincosf(ax, &sx, &cxs);
    sincosf(ay, &sy, &cys);
    row[f * 4 + 0] = sx; row[f * 4 + 1] = cxs;
    row[f * 4 + 2] = sy; row[f * 4 + 3] = cys;
    fr = fr * 2.0f;
  }
  float4* dst = (float4*)(enc + (size_t)tid * 40);
#pragma unroll
  for (int i = 0; i < 10; i++)
    dst[i] = make_float4(row[4 * i], row[4 * i + 1], row[4 * i + 2], row[4 * i + 3]);
}

// ---------------- zero the stat accumulators (ws is poisoned) ----------------
__global__ void zero_stats(float* __restrict__ s1, float* __restrict__ s2) {
  int t = threadIdx.x;
  if (t < 128) s1[t] = 0.f;
  s2[t] = 0.f;   // 256 threads cover 256
}

// ---------------- GEMM1 + BN1 stats (Z1 discarded) ----------------
__global__ __launch_bounds__(256)
void gemm1_stats(const float* __restrict__ enc, const float* __restrict__ W1,
                 const float* __restrict__ b1, float* __restrict__ stats1) {
  __shared__ float w1t[64 * 40];   // transposed: w1t[c*40+k]
  __shared__ float b1s[64];
  __shared__ float acc[128];
  const int t = threadIdx.x;
  for (int i = t; i < 2560; i += 256) { int c = i / 40, k = i % 40; w1t[i] = W1[k * 64 + c]; }
  if (t < 64) b1s[t] = b1[t];
  if (t < 128) acc[t] = 0.f;
  __syncthreads();
  const int row = blockIdx.x * 256 + t;
  const int lane = t & 63;
  float x[40];
  const float4* er = (const float4*)(enc + (size_t)row * 40);
#pragma unroll
  for (int i = 0; i < 10; i++) { float4 v = er[i]; x[4*i]=v.x; x[4*i+1]=v.y; x[4*i+2]=v.z; x[4*i+3]=v.w; }
  for (int c = 0; c < 64; c++) {
    float z = b1s[c];
    const float4* wc = (const float4*)(w1t + c * 40);
#pragma unroll
    for (int q = 0; q < 10; q++) {
      float4 w = wc[q];
      z += x[4*q]*w.x + x[4*q+1]*w.y + x[4*q+2]*w.z + x[4*q+3]*w.w;
    }
    float s = z, s2 = z * z;
#pragma unroll
    for (int off = 32; off > 0; off >>= 1) { s += __shfl_down(s, off); s2 += __shfl_down(s2, off); }
    if (lane == 0) { atomicAdd(&acc[c], s); atomicAdd(&acc[64 + c], s2); }
  }
  __syncthreads();
  if (t < 128) atomicAdd(&stats1[t], acc[t]);
}

// ---------------- finalize BN params: a = g*rsqrt(var+eps), b' = be - a*mu ----
__global__ void finalize_bn(const float* __restrict__ stats, const float* __restrict__ g,
                            const float* __restrict__ be, float* __restrict__ ab, int C) {
  int c = threadIdx.x;
  if (c < C) {
    const float invN = 1.0f / (float)NROWS;
    float mu = stats[c] * invN;
    float var = stats[C + c] * invN - mu * mu;
    float a = g[c] * rsqrtf(var + BN_EPS);
    ab[c] = a; ab[C + c] = be[c] - a * mu;
  }
}

// ---------------- GEMM1->BN1->relu->GEMM2 + BN2 stats (Z2 discarded) --------
__global__ __launch_bounds__(256)
void gemm2_stats(const float* __restrict__ enc, const float* __restrict__ W1,
                 const float* __restrict__ b1, const float* __restrict__ ab1,
                 const float* __restrict__ W2, const float* __restrict__ b2,
                 float* __restrict__ stats2) {
  __shared__ float w1t[64 * 40];    // [c][k]
  __shared__ float w2t[128 * 64];   // [c2][j]
  __shared__ float b1s[64], b2s[128], ab1s[128];
  __shared__ float acc[256];
  const int t = threadIdx.x;
  for (int i = t; i < 2560; i += 256) { int c = i / 40, k = i % 40; w1t[i] = W1[k * 64 + c]; }
  for (int i = t; i < 8192; i += 256) { int c = i / 64, j = i % 64; w2t[i] = W2[j * 128 + c]; }
  if (t < 64) b1s[t] = b1[t];
  if (t < 128) { b2s[t] = b2[t]; ab1s[t] = ab1[t]; }
  if (t < 64) ab1s[64 + t] = ab1[64 + t];
  acc[t] = 0.f;
  __syncthreads();
  const int row = blockIdx.x * 256 + t;
  const int lane = t & 63;
  float x[40];
  const float4* er = (const float4*)(enc + (size_t)row * 40);
#pragma unroll
  for (int i = 0; i < 10; i++) { float4 v = er[i]; x[4*i]=v.x; x[4*i+1]=v.y; x[4*i+2]=v.z; x[4*i+3]=v.w; }
  float h[64];
  for (int c = 0; c < 64; c++) {
    float z = b1s[c];
    const float4* wc = (const float4*)(w1t + c * 40);
#pragma unroll
    for (int q = 0; q < 10; q++) {
      float4 w = wc[q];
      z += x[4*q]*w.x + x[4*q+1]*w.y + x[4*q+2]*w.z + x[4*q+3]*w.w;
    }
    h[c] = fmaxf(fmaf(ab1s[c], z, ab1s[64 + c]), 0.f);
  }
  for (int c = 0; c < 128; c++) {
    float z = b2s[c];
    const float4* wc = (const float4*)(w2t + c * 64);
#pragma unroll
    for (int q = 0; q < 16; q++) {
      float4 w = wc[q];
      z += h[4*q]*w.x + h[4*q+1]*w.y + h[4*q+2]*w.z + h[4*q+3]*w.w;
    }
    float s = z, s2 = z * z;
#pragma unroll
    for (int off = 32; off > 0; off >>= 1) { s += __shfl_down(s, off); s2 += __shfl_down(s2, off); }
    if (lane == 0) { atomicAdd(&acc[c], s); atomicAdd(&acc[128 + c], s2); }
  }
  __syncthreads();
  atomicAdd(&stats2[t], acc[t]);
}

// ---------------- full MLP + group max ----------------
__global__ __launch_bounds__(256)
void final_kernel(const float* __restrict__ enc, const float* __restrict__ W1,
                  const float* __restrict__ b1, const float* __restrict__ ab1,
                  const float* __restrict__ W2, const float* __restrict__ b2,
                  const float* __restrict__ ab2, const float* __restrict__ W3,
                  const float* __restrict__ b3, float* __restrict__ out_feat) {
  __shared__ float w1t[64 * 40];
  __shared__ float w2t[128 * 64];
  __shared__ float w3s[128 * 16];
  __shared__ float b1s[64], b2s[128], b3s[16], ab1s[128], ab2s[256];
  __shared__ float srow[256][16];
  const int t = threadIdx.x;
  for (int i = t; i < 2560; i += 256) { int c = i / 40, k = i % 40; w1t[i] = W1[k * 64 + c]; }
  for (int i = t; i < 8192; i += 256) { int c = i / 64, j = i % 64; w2t[i] = W2[j * 128 + c]; }
  for (int i = t; i < 2048; i += 256) w3s[i] = W3[i];
  if (t < 64) b1s[t] = b1[t];
  if (t < 128) { b2s[t] = b2[t]; ab1s[t] = ab1[t]; }
  if (t < 64) ab1s[64 + t] = ab1[64 + t];
  ab2s[t] = ab2[t];
  if (t < 16) b3s[t] = b3[t];
  __syncthreads();
  const int row = blockIdx.x * 256 + t;
  float x[40];
  const float4* er = (const float4*)(enc + (size_t)row * 40);
#pragma unroll
  for (int i = 0; i < 10; i++) { float4 v = er[i]; x[4*i]=v.x; x[4*i+1]=v.y; x[4*i+2]=v.z; x[4*i+3]=v.w; }
  float h[64];
  for (int c = 0; c < 64; c++) {
    float z = b1s[c];
    const float4* wc = (const float4*)(w1t + c * 40);
#pragma unroll
    for (int q = 0; q < 10; q++) {
      float4 w = wc[q];
      z += x[4*q]*w.x + x[4*q+1]*w.y + x[4*q+2]*w.z + x[4*q+3]*w.w;
    }
    h[c] = fmaxf(fmaf(ab1s[c], z, ab1s[64 + c]), 0.f);
  }
  float acc[16];
#pragma unroll
  for (int o = 0; o < 16; o++) acc[o] = b3s[o];
  for (int j = 0; j < 128; j++) {
    float z = b2s[j];
    const float4* wc = (const float4*)(w2t + j * 64);
#pragma unroll
    for (int q = 0; q < 16; q++) {
      float4 w = wc[q];
      z += h[4*q]*w.x + h[4*q+1]*w.y + h[4*q+2]*w.z + h[4*q+3]*w.w;
    }
    float h2 = fmaxf(fmaf(ab2s[j], z, ab2s[128 + j]), 0.f);
    const float4* w3r = (const float4*)(w3s + j * 16);
#pragma unroll
    for (int q = 0; q < 4; q++) {
      float4 w = w3r[q];
      acc[4*q] += h2 * w.x; acc[4*q+1] += h2 * w.y; acc[4*q+2] += h2 * w.z; acc[4*q+3] += h2 * w.w;
    }
  }
#pragma unroll
  for (int o = 0; o < 16; o++) srow[t][o] = acc[o];
  __syncthreads();
  if (t < 128) {
    const int g = t >> 4, c = t & 15;
    float mx = srow[g * 32][c];
#pragma unroll
    for (int r = 1; r < 32; r++) mx = fmaxf(mx, srow[g * 32 + r][c]);
    out_feat[(size_t)(blockIdx.x * 8 + g) * 16 + c] = mx;
  }
}

// ---------------- host launcher ----------------
extern "C" void kernel_launch(void* const* d_in, const int* in_sizes, int n_in,
                              void* d_out, int out_size, void* d_ws, size_t ws_size,
                              hipStream_t stream) {
  const float* pts = (const float*)d_in[0];
  const float* W1 = (const float*)d_in[1];  const float* b1 = (const float*)d_in[2];
  const float* g1 = (const float*)d_in[3];  const float* be1 = (const float*)d_in[4];
  const float* W2 = (const float*)d_in[5];  const float* b2 = (const float*)d_in[6];
  const float* g2 = (const float*)d_in[7];  const float* be2 = (const float*)d_in[8];
  const float* W3 = (const float*)d_in[9];  const float* b3 = (const float*)d_in[10];
  float* out = (float*)d_out;   // [2048*16 features | 2048*2 centroids]

  char* w = (char*)d_ws;
  auto carve = [&](size_t bytes) -> char* {
    char* p = w;
    w += (bytes + 255) & ~(size_t)255;
    return p;
  };
  unsigned long long* slotA = (unsigned long long*)carve(2 * FPS_NB * 8);
  unsigned long long* slotB = (unsigned long long*)carve(2 * FPS_NB * 8);
  float*    cents  = (float*)carve((size_t)M_CENT * 2 * 4);
  int*      assign = (int*)carve((size_t)N_PTS * 4);
  unsigned char* ranks = (unsigned char*)carve((size_t)N_PTS);
  unsigned* gcounts = (unsigned*)carve((size_t)NCHUNK * M_CENT * 4);
  unsigned* counts  = (unsigned*)carve((size_t)M_CENT * 4);
  int*      sel     = (int*)carve((size_t)M_CENT * K_GRP * 4);
  float*    enc     = (float*)carve((size_t)NROWS * 40 * 4);
  float*    stats1  = (float*)carve(128 * 4);
  float*    stats2  = (float*)carve(256 * 4);
  float*    ab1     = (float*)carve(128 * 4);
  float*    ab2     = (float*)carve(256 * 4);

  float* out_feat = out;
  float* out_cent = out + (size_t)M_CENT * 16;

  hipLaunchKernelGGL(zero_stats, dim3(1), dim3(256), 0, stream, stats1, stats2);
  hipLaunchKernelGGL(fps_kernel, dim3(FPS_NB), dim3(FPS_NT), 0, stream,
                     pts, cents, out_cent, slotA, slotB);
  hipLaunchKernelGGL(assign_kernel, dim3(N_PTS / 256), dim3(256), 0, stream,
                     pts, cents, assign);
  hipLaunchKernelGGL(hist_kernel, dim3(NCHUNK), dim3(256), 0, stream,
                     assign, gcounts, ranks);
  hipLaunchKernelGGL(scan_kernel, dim3(M_CENT / 256), dim3(256), 0, stream,
                     gcounts, counts);
  hipLaunchKernelGGL(scatter_kernel, dim3(NCHUNK), dim3(256), 0, stream,
                     assign, ranks, gcounts, sel);
  hipLaunchKernelGGL(encode_kernel, dim3(NROWS / 256), dim3(256), 0, stream,
                     pts, cents, sel, counts, enc);
  hipLaunchKernelGGL(gemm1_stats, dim3(NROWS / 256), dim3(256), 0, stream,
                     enc, W1, b1, stats1);
  hipLaunchKernelGGL(finalize_bn, dim3(1), dim3(64), 0, stream, stats1, g1, be1, ab1, 64);
  hipLaunchKernelGGL(gemm2_stats, dim3(NROWS / 256), dim3(256), 0, stream,
                     enc, W1, b1, ab1, W2, b2, stats2);
  hipLaunchKernelGGL(finalize_bn, dim3(1), dim3(128), 0, stream, stats2, g2, be2, ab2, 128);
  hipLaunchKernelGGL(final_kernel, dim3(NROWS / 256), dim3(256), 0, stream,
                     enc, W1, b1, ab1, W2, b2, ab2, W3, b3, out_feat);
}

// Round 2
// 6210.667 us; speedup vs baseline: 1.1495x; 1.1495x over previous
//
#include <hip/hip_runtime.h>
#include <hip/hip_bf16.h>
#include <math.h>

#define N_PTS   131072
#define M_CENT  2048
#define K_GRP   32
#define NSTEP   2047          // num_samples - 1
#define NROWS   (M_CENT * K_GRP)   // 65536
#define NCHUNK  512           // chunks of 256 points
#define BN_EPS  1e-5f

// ---------------- FPS persistent kernel ----------------
#define FPS_NB 32
#define FPS_NT 256
#define FPS_PPT (N_PTS / (FPS_NB * FPS_NT))   // 16
#define FPS_NW (FPS_NT / 64)                  // 4 waves

// Exchange word: [dist_bits:32 | tag:15 | (131071-idx):17]
//  - dist >= 0 so float bits are monotone as uint
//  - tag = step+1 (1..2047); 0xAA poison decodes tag 0x5555=21845 -> never matches
//  - inverted idx: max-reduce prefers LOWEST point index on exact dist ties
//  - single 8B store/load = one L2/IF$ transaction: tag+payload can't tear
__global__ __launch_bounds__(FPS_NT)
void fps_kernel(const float* __restrict__ pts, float* __restrict__ cents,
                float* __restrict__ outc, unsigned long long* __restrict__ slots) {
  const int b = blockIdx.x, t = threadIdx.x;
  const int lane = t & 63, wid = t >> 6;
  float px[FPS_PPT], py[FPS_PPT], dist[FPS_PPT];
  const int gbase = b * FPS_NT + t;
#pragma unroll
  for (int k = 0; k < FPS_PPT; k++) {
    int g = gbase + k * (FPS_NB * FPS_NT);
    px[k] = pts[2 * g]; py[k] = pts[2 * g + 1];
    dist[k] = __builtin_inff();
  }
  float cx = pts[0], cy = pts[1];
  if (b == 0 && t == 0) { cents[0] = cx; cents[1] = cy; outc[0] = cx; outc[1] = cy; }
  __shared__ unsigned long long lred[FPS_NW];
  __shared__ float s_cx, s_cy;

  for (int s = 0; s < NSTEP; s++) {
    const unsigned tag = (unsigned)(s + 1);
    // ---- local distance update + thread-local argmax (float compare) ----
    float bestd = -1.0f; int bestk = 0;
#pragma unroll
    for (int k = 0; k < FPS_PPT; k++) {
      // exactly match reference: nd = sqrt(dx*dx + dy*dy), no fma contraction
      float dx = __fsub_rn(px[k], cx), dy = __fsub_rn(py[k], cy);
      float d2 = __fadd_rn(__fmul_rn(dx, dx), __fmul_rn(dy, dy));
      float nd = __fsqrt_rn(d2);              // correctly-rounded sqrt
      float dm = fminf(dist[k], nd);
      dist[k] = dm;
      if (dm > bestd) { bestd = dm; bestk = k; }   // strict > : lowest k on tie
    }
    const int bg = gbase + bestk * (FPS_NB * FPS_NT);
    unsigned long long key = ((unsigned long long)__float_as_uint(bestd) << 32)
                           | ((unsigned long long)tag << 17)
                           | (unsigned)(N_PTS - 1 - bg);
    // ---- wave max-reduce (u64 key only) ----
#pragma unroll
    for (int off = 32; off > 0; off >>= 1) {
      unsigned long long ok = __shfl_down(key, off);
      if (ok > key) key = ok;
    }
    if (lane == 0) lred[wid] = key;
    __syncthreads();
    if (wid == 0) {
      key = (lane < FPS_NW) ? lred[lane] : 0ull;
#pragma unroll
      for (int off = FPS_NW / 2; off > 0; off >>= 1) {
        unsigned long long ok = __shfl_down(key, off);
        if (ok > key) key = ok;
      }
      // double-buffered slots by step parity: a block only writes step s+2
      // after consuming all step-s+1 slots (store value is data-dependent on
      // those loads), and every s+1 writer consumed all step-s slots first.
      unsigned long long* sl = slots + (s & 1) * FPS_NB;
      if (lane == 0) {
        unsigned long long* ad = &sl[b];
        asm volatile("global_store_dwordx2 %0, %1, off sc0 sc1"
                     :: "v"(ad), "v"(key) : "memory");
      }
      unsigned long long gk = 0ull;
      if (lane < FPS_NB) {
        unsigned long long* ad = &sl[lane];
        unsigned long long v;
        do {
          asm volatile("global_load_dwordx2 %0, %1, off sc0 sc1\n\ts_waitcnt vmcnt(0)"
                       : "=v"(v) : "v"(ad) : "memory");
        } while (((unsigned)v >> 17) != tag);
        gk = v;
      }
#pragma unroll
      for (int off = FPS_NB / 2; off > 0; off >>= 1) {
        unsigned long long ok = __shfl_down(gk, off);
        if (ok > gk) gk = ok;
      }
      if (lane == 0) {
        int idx = N_PTS - 1 - (int)(gk & 0x1FFFFull);
        float gx = pts[2 * idx], gy = pts[2 * idx + 1];   // L2-resident
        s_cx = gx; s_cy = gy;
        if (b == 0) {
          cents[2 * (s + 1)] = gx; cents[2 * (s + 1) + 1] = gy;
          outc[2 * (s + 1)] = gx;  outc[2 * (s + 1) + 1] = gy;
        }
      }
    }
    __syncthreads();
    cx = s_cx; cy = s_cy;
  }
}

// ---------------- nearest-centroid assignment ----------------
__global__ __launch_bounds__(256)
void assign_kernel(const float* __restrict__ pts, const float* __restrict__ cents,
                   int* __restrict__ assign) {
  __shared__ float scx[M_CENT], scy[M_CENT], sc2[M_CENT];
  const int t = threadIdx.x;
  for (int i = t; i < M_CENT; i += 256) {
    float x = cents[2 * i], y = cents[2 * i + 1];
    scx[i] = x; scy[i] = y;
    sc2[i] = __fadd_rn(__fmul_rn(x, x), __fmul_rn(y, y));
  }
  __syncthreads();
  const int n = blockIdx.x * 256 + t;
  float x = pts[2 * n], y = pts[2 * n + 1];
  float p2 = __fadd_rn(__fmul_rn(x, x), __fmul_rn(y, y));
  float best = __builtin_inff(); int bm = 0;
  for (int m = 0; m < M_CENT; m++) {
    // reference formula: (p2 + c2) - 2*(p.c), no fma
    float dot = __fadd_rn(__fmul_rn(x, scx[m]), __fmul_rn(y, scy[m]));
    float d2 = __fsub_rn(__fadd_rn(p2, sc2[m]), __fmul_rn(2.0f, dot));
    if (d2 < best) { best = d2; bm = m; }   // strict < : first-min tie-break
  }
  assign[n] = bm;
}

// ---------------- chunk histogram + intra-chunk stable rank ----------------
__global__ __launch_bounds__(256)
void hist_kernel(const int* __restrict__ assign, unsigned* __restrict__ gcounts,
                 unsigned char* __restrict__ ranks) {
  __shared__ unsigned hist[M_CENT];
  __shared__ int sa[256];
  const int t = threadIdx.x, c = blockIdx.x;
  for (int i = t; i < M_CENT; i += 256) hist[i] = 0u;
  __syncthreads();
  const int n = c * 256 + t;
  const int m = assign[n];
  sa[t] = m;
  atomicAdd(&hist[m], 1u);
  __syncthreads();
  int r = 0;
  for (int j = 0; j < t; j++) r += (sa[j] == m);   // broadcast LDS reads
  ranks[n] = (unsigned char)r;
  for (int i = t; i < M_CENT; i += 256) gcounts[(size_t)c * M_CENT + i] = hist[i];
}

// ---------------- per-centroid exclusive scan over chunks ----------------
__global__ __launch_bounds__(256)
void scan_kernel(unsigned* __restrict__ gcounts, unsigned* __restrict__ counts) {
  const int m = blockIdx.x * 256 + threadIdx.x;   // 8 blocks -> 2048 centroids
  unsigned run = 0;
  for (int ch = 0; ch < NCHUNK; ch++) {
    unsigned v = gcounts[(size_t)ch * M_CENT + m];
    gcounts[(size_t)ch * M_CENT + m] = run;
    run += v;
  }
  counts[m] = run;
}

// ---------------- scatter first-32 (lowest-index) per centroid ----------------
__global__ __launch_bounds__(256)
void scatter_kernel(const int* __restrict__ assign, const unsigned char* __restrict__ ranks,
                    const unsigned* __restrict__ gexcl, int* __restrict__ sel) {
  const int n = blockIdx.x * 256 + threadIdx.x;
  const int m = assign[n];
  unsigned pos = gexcl[(size_t)blockIdx.x * M_CENT + m] + (unsigned)ranks[n];
  if (pos < K_GRP) sel[m * K_GRP + pos] = n;
}

// ---------------- gather + HF encoding ----------------
__global__ __launch_bounds__(256)
void encode_kernel(const float* __restrict__ pts, const float* __restrict__ cents,
                   const int* __restrict__ sel, const unsigned* __restrict__ counts,
                   float* __restrict__ enc) {
  const int tid = blockIdx.x * 256 + threadIdx.x;   // 0..65535
  const int m = tid >> 5, k = tid & 31;
  const unsigned cnt = counts[m];
  const float cx = cents[2 * m], cy = cents[2 * m + 1];
  float rx, ry;
  if (cnt == 0u) {
    if (k == 0) { rx = 0.f; ry = 0.f; }             // slot0 = centroid -> rel 0
    else        { rx = 0.f - cx; ry = 0.f - cy; }   // others grouped=0 -> rel=-c
  } else {
    int kk = ((unsigned)k < cnt) ? k : (int)cnt - 1;  // pad with last assigned
    int n = sel[m * K_GRP + kk];
    rx = __fsub_rn(pts[2 * n], cx);
    ry = __fsub_rn(pts[2 * n + 1], cy);
  }
  float row[40];
  float fr = 3.14159265358979323846f;   // rounds to float(pi); doubling is exact
#pragma unroll
  for (int f = 0; f < 10; f++) {
    float ax = __fmul_rn(rx, fr), ay = __fmul_rn(ry, fr);
    float sx, cxs, sy, cys;
    sincosf(ax, &sx, &cxs);
    sincosf(ay, &sy, &cys);
    row[f * 4 + 0] = sx; row[f * 4 + 1] = cxs;
    row[f * 4 + 2] = sy; row[f * 4 + 3] = cys;
    fr = fr * 2.0f;
  }
  float4* dst = (float4*)(enc + (size_t)tid * 40);
#pragma unroll
  for (int i = 0; i < 10; i++)
    dst[i] = make_float4(row[4 * i], row[4 * i + 1], row[4 * i + 2], row[4 * i + 3]);
}

// ---------------- zero the stat accumulators (ws is poisoned) ----------------
__global__ void zero_stats(float* __restrict__ s1, float* __restrict__ s2) {
  int t = threadIdx.x;
  if (t < 128) s1[t] = 0.f;
  s2[t] = 0.f;   // 256 threads cover 256
}

// ---------------- GEMM1 + BN1 stats (Z1 discarded) ----------------
__global__ __launch_bounds__(256)
void gemm1_stats(const float* __restrict__ enc, const float* __restrict__ W1,
                 const float* __restrict__ b1, float* __restrict__ stats1) {
  __shared__ float w1t[64 * 40];   // transposed: w1t[c*40+k]
  __shared__ float b1s[64];
  __shared__ float acc[128];
  const int t = threadIdx.x;
  for (int i = t; i < 2560; i += 256) { int c = i / 40, k = i % 40; w1t[i] = W1[k * 64 + c]; }
  if (t < 64) b1s[t] = b1[t];
  if (t < 128) acc[t] = 0.f;
  __syncthreads();
  const int row = blockIdx.x * 256 + t;
  const int lane = t & 63;
  float x[40];
  const float4* er = (const float4*)(enc + (size_t)row * 40);
#pragma unroll
  for (int i = 0; i < 10; i++) { float4 v = er[i]; x[4*i]=v.x; x[4*i+1]=v.y; x[4*i+2]=v.z; x[4*i+3]=v.w; }
  for (int c = 0; c < 64; c++) {
    float z = b1s[c];
    const float4* wc = (const float4*)(w1t + c * 40);
#pragma unroll
    for (int q = 0; q < 10; q++) {
      float4 w = wc[q];
      z += x[4*q]*w.x + x[4*q+1]*w.y + x[4*q+2]*w.z + x[4*q+3]*w.w;
    }
    float s = z, s2 = z * z;
#pragma unroll
    for (int off = 32; off > 0; off >>= 1) { s += __shfl_down(s, off); s2 += __shfl_down(s2, off); }
    if (lane == 0) { atomicAdd(&acc[c], s); atomicAdd(&acc[64 + c], s2); }
  }
  __syncthreads();
  if (t < 128) atomicAdd(&stats1[t], acc[t]);
}

// ---------------- finalize BN params: a = g*rsqrt(var+eps), b' = be - a*mu ----
__global__ void finalize_bn(const float* __restrict__ stats, const float* __restrict__ g,
                            const float* __restrict__ be, float* __restrict__ ab, int C) {
  int c = threadIdx.x;
  if (c < C) {
    const float invN = 1.0f / (float)NROWS;
    float mu = stats[c] * invN;
    float var = stats[C + c] * invN - mu * mu;
    float a = g[c] * rsqrtf(var + BN_EPS);
    ab[c] = a; ab[C + c] = be[c] - a * mu;
  }
}

// ---------------- GEMM1->BN1->relu->GEMM2 + BN2 stats (Z2 discarded) --------
__global__ __launch_bounds__(256)
void gemm2_stats(const float* __restrict__ enc, const float* __restrict__ W1,
                 const float* __restrict__ b1, const float* __restrict__ ab1,
                 const float* __restrict__ W2, const float* __restrict__ b2,
                 float* __restrict__ stats2) {
  __shared__ float w1t[64 * 40];    // [c][k]
  __shared__ float w2t[128 * 64];   // [c2][j]
  __shared__ float b1s[64], b2s[128], ab1s[128];
  __shared__ float acc[256];
  const int t = threadIdx.x;
  for (int i = t; i < 2560; i += 256) { int c = i / 40, k = i % 40; w1t[i] = W1[k * 64 + c]; }
  for (int i = t; i < 8192; i += 256) { int c = i / 64, j = i % 64; w2t[i] = W2[j * 128 + c]; }
  if (t < 64) b1s[t] = b1[t];
  if (t < 128) { b2s[t] = b2[t]; ab1s[t] = ab1[t]; }
  if (t < 64) ab1s[64 + t] = ab1[64 + t];
  acc[t] = 0.f;
  __syncthreads();
  const int row = blockIdx.x * 256 + t;
  const int lane = t & 63;
  float x[40];
  const float4* er = (const float4*)(enc + (size_t)row * 40);
#pragma unroll
  for (int i = 0; i < 10; i++) { float4 v = er[i]; x[4*i]=v.x; x[4*i+1]=v.y; x[4*i+2]=v.z; x[4*i+3]=v.w; }
  float h[64];
  for (int c = 0; c < 64; c++) {
    float z = b1s[c];
    const float4* wc = (const float4*)(w1t + c * 40);
#pragma unroll
    for (int q = 0; q < 10; q++) {
      float4 w = wc[q];
      z += x[4*q]*w.x + x[4*q+1]*w.y + x[4*q+2]*w.z + x[4*q+3]*w.w;
    }
    h[c] = fmaxf(fmaf(ab1s[c], z, ab1s[64 + c]), 0.f);
  }
  for (int c = 0; c < 128; c++) {
    float z = b2s[c];
    const float4* wc = (const float4*)(w2t + c * 64);
#pragma unroll
    for (int q = 0; q < 16; q++) {
      float4 w = wc[q];
      z += h[4*q]*w.x + h[4*q+1]*w.y + h[4*q+2]*w.z + h[4*q+3]*w.w;
    }
    float s = z, s2 = z * z;
#pragma unroll
    for (int off = 32; off > 0; off >>= 1) { s += __shfl_down(s, off); s2 += __shfl_down(s2, off); }
    if (lane == 0) { atomicAdd(&acc[c], s); atomicAdd(&acc[128 + c], s2); }
  }
  __syncthreads();
  atomicAdd(&stats2[t], acc[t]);
}

// ---------------- full MLP + group max ----------------
__global__ __launch_bounds__(256)
void final_kernel(const float* __restrict__ enc, const float* __restrict__ W1,
                  const float* __restrict__ b1, const float* __restrict__ ab1,
                  const float* __restrict__ W2, const float* __restrict__ b2,
                  const float* __restrict__ ab2, const float* __restrict__ W3,
                  const float* __restrict__ b3, float* __restrict__ out_feat) {
  __shared__ float w1t[64 * 40];
  __shared__ float w2t[128 * 64];
  __shared__ float w3s[128 * 16];
  __shared__ float b1s[64], b2s[128], b3s[16], ab1s[128], ab2s[256];
  __shared__ float srow[256][16];
  const int t = threadIdx.x;
  for (int i = t; i < 2560; i += 256) { int c = i / 40, k = i % 40; w1t[i] = W1[k * 64 + c]; }
  for (int i = t; i < 8192; i += 256) { int c = i / 64, j = i % 64; w2t[i] = W2[j * 128 + c]; }
  for (int i = t; i < 2048; i += 256) w3s[i] = W3[i];
  if (t < 64) b1s[t] = b1[t];
  if (t < 128) { b2s[t] = b2[t]; ab1s[t] = ab1[t]; }
  if (t < 64) ab1s[64 + t] = ab1[64 + t];
  ab2s[t] = ab2[t];
  if (t < 16) b3s[t] = b3[t];
  __syncthreads();
  const int row = blockIdx.x * 256 + t;
  float x[40];
  const float4* er = (const float4*)(enc + (size_t)row * 40);
#pragma unroll
  for (int i = 0; i < 10; i++) { float4 v = er[i]; x[4*i]=v.x; x[4*i+1]=v.y; x[4*i+2]=v.z; x[4*i+3]=v.w; }
  float h[64];
  for (int c = 0; c < 64; c++) {
    float z = b1s[c];
    const float4* wc = (const float4*)(w1t + c * 40);
#pragma unroll
    for (int q = 0; q < 10; q++) {
      float4 w = wc[q];
      z += x[4*q]*w.x + x[4*q+1]*w.y + x[4*q+2]*w.z + x[4*q+3]*w.w;
    }
    h[c] = fmaxf(fmaf(ab1s[c], z, ab1s[64 + c]), 0.f);
  }
  float acc[16];
#pragma unroll
  for (int o = 0; o < 16; o++) acc[o] = b3s[o];
  for (int j = 0; j < 128; j++) {
    float z = b2s[j];
    const float4* wc = (const float4*)(w2t + j * 64);
#pragma unroll
    for (int q = 0; q < 16; q++) {
      float4 w = wc[q];
      z += h[4*q]*w.x + h[4*q+1]*w.y + h[4*q+2]*w.z + h[4*q+3]*w.w;
    }
    float h2 = fmaxf(fmaf(ab2s[j], z, ab2s[128 + j]), 0.f);
    const float4* w3r = (const float4*)(w3s + j * 16);
#pragma unroll
    for (int q = 0; q < 4; q++) {
      float4 w = w3r[q];
      acc[4*q] += h2 * w.x; acc[4*q+1] += h2 * w.y; acc[4*q+2] += h2 * w.z; acc[4*q+3] += h2 * w.w;
    }
  }
#pragma unroll
  for (int o = 0; o < 16; o++) srow[t][o] = acc[o];
  __syncthreads();
  if (t < 128) {
    const int g = t >> 4, c = t & 15;
    float mx = srow[g * 32][c];
#pragma unroll
    for (int r = 1; r < 32; r++) mx = fmaxf(mx, srow[g * 32 + r][c]);
    out_feat[(size_t)(blockIdx.x * 8 + g) * 16 + c] = mx;
  }
}

// ---------------- host launcher ----------------
extern "C" void kernel_launch(void* const* d_in, const int* in_sizes, int n_in,
                              void* d_out, int out_size, void* d_ws, size_t ws_size,
                              hipStream_t stream) {
  const float* pts = (const float*)d_in[0];
  const float* W1 = (const float*)d_in[1];  const float* b1 = (const float*)d_in[2];
  const float* g1 = (const float*)d_in[3];  const float* be1 = (const float*)d_in[4];
  const float* W2 = (const float*)d_in[5];  const float* b2 = (const float*)d_in[6];
  const float* g2 = (const float*)d_in[7];  const float* be2 = (const float*)d_in[8];
  const float* W3 = (const float*)d_in[9];  const float* b3 = (const float*)d_in[10];
  float* out = (float*)d_out;   // [2048*16 features | 2048*2 centroids]

  char* w = (char*)d_ws;
  auto carve = [&](size_t bytes) -> char* {
    char* p = w;
    w += (bytes + 255) & ~(size_t)255;
    return p;
  };
  unsigned long long* slots = (unsigned long long*)carve(2 * FPS_NB * 8);
  float*    cents  = (float*)carve((size_t)M_CENT * 2 * 4);
  int*      assign = (int*)carve((size_t)N_PTS * 4);
  unsigned char* ranks = (unsigned char*)carve((size_t)N_PTS);
  unsigned* gcounts = (unsigned*)carve((size_t)NCHUNK * M_CENT * 4);
  unsigned* counts  = (unsigned*)carve((size_t)M_CENT * 4);
  int*      sel     = (int*)carve((size_t)M_CENT * K_GRP * 4);
  float*    enc     = (float*)carve((size_t)NROWS * 40 * 4);
  float*    stats1  = (float*)carve(128 * 4);
  float*    stats2  = (float*)carve(256 * 4);
  float*    ab1     = (float*)carve(128 * 4);
  float*    ab2     = (float*)carve(256 * 4);

  float* out_feat = out;
  float* out_cent = out + (size_t)M_CENT * 16;

  hipLaunchKernelGGL(zero_stats, dim3(1), dim3(256), 0, stream, stats1, stats2);
  hipLaunchKernelGGL(fps_kernel, dim3(FPS_NB), dim3(FPS_NT), 0, stream,
                     pts, cents, out_cent, slots);
  hipLaunchKernelGGL(assign_kernel, dim3(N_PTS / 256), dim3(256), 0, stream,
                     pts, cents, assign);
  hipLaunchKernelGGL(hist_kernel, dim3(NCHUNK), dim3(256), 0, stream,
                     assign, gcounts, ranks);
  hipLaunchKernelGGL(scan_kernel, dim3(M_CENT / 256), dim3(256), 0, stream,
                     gcounts, counts);
  hipLaunchKernelGGL(scatter_kernel, dim3(NCHUNK), dim3(256), 0, stream,
                     assign, ranks, gcounts, sel);
  hipLaunchKernelGGL(encode_kernel, dim3(NROWS / 256), dim3(256), 0, stream,
                     pts, cents, sel, counts, enc);
  hipLaunchKernelGGL(gemm1_stats, dim3(NROWS / 256), dim3(256), 0, stream,
                     enc, W1, b1, stats1);
  hipLaunchKernelGGL(finalize_bn, dim3(1), dim3(64), 0, stream, stats1, g1, be1, ab1, 64);
  hipLaunchKernelGGL(gemm2_stats, dim3(NROWS / 256), dim3(256), 0, stream,
                     enc, W1, b1, ab1, W2, b2, stats2);
  hipLaunchKernelGGL(finalize_bn, dim3(1), dim3(128), 0, stream, stats2, g2, be2, ab2, 128);
  hipLaunchKernelGGL(final_kernel, dim3(NROWS / 256), dim3(256), 0, stream,
                     enc, W1, b1, ab1, W2, b2, ab2, W3, b3, out_feat);
}

// Round 3
// 5258.501 us; speedup vs baseline: 1.3576x; 1.1811x over previous
//
#include <hip/hip_runtime.h>
#include <hip/hip_bf16.h>
#include <math.h>

#define N_PTS   131072
#define M_CENT  2048
#define K_GRP   32
#define NSTEP   2047          // num_samples - 1
#define NROWS   (M_CENT * K_GRP)   // 65536
#define NCHUNK  512           // chunks of 256 points
#define BN_EPS  1e-5f

// ---------------- FPS persistent kernel ----------------
#define FPS_NB 32
#define FPS_NT 256
#define FPS_PPT (N_PTS / (FPS_NB * FPS_NT))   // 16
#define FPS_NW (FPS_NT / 64)                  // 4 waves
#define SLOT_STRIDE 16        // 16 u64 = 128 B: one slot per cache line

// Exchange word: [dist_bits:32 | tag:15 | (131071-idx):17]
//  - dist >= 0 so float bits are monotone as uint
//  - tag = step+1 (1..2047); 0xAA poison decodes tag 0x5555=21845 -> never matches
//  - inverted idx: max-reduce prefers LOWEST point index on exact dist ties
//  - single 8B store/load = one transaction: tag+payload can't tear
//  - each slot on its OWN 128B line: no line ping-pong between writers/pollers
__global__ __launch_bounds__(FPS_NT)
void fps_kernel(const float* __restrict__ pts, float* __restrict__ cents,
                float* __restrict__ outc, unsigned long long* __restrict__ slots) {
  const int b = blockIdx.x, t = threadIdx.x;
  const int lane = t & 63, wid = t >> 6;
  float px[FPS_PPT], py[FPS_PPT], dist[FPS_PPT];
  const int gbase = b * FPS_NT + t;
#pragma unroll
  for (int k = 0; k < FPS_PPT; k++) {
    int g = gbase + k * (FPS_NB * FPS_NT);
    px[k] = pts[2 * g]; py[k] = pts[2 * g + 1];
    dist[k] = __builtin_inff();
  }
  float cx = pts[0], cy = pts[1];
  if (b == 0 && t == 0) { cents[0] = cx; cents[1] = cy; outc[0] = cx; outc[1] = cy; }
  __shared__ unsigned long long lred[FPS_NW];
  __shared__ float s_cx, s_cy;

  for (int s = 0; s < NSTEP; s++) {
    const unsigned tag = (unsigned)(s + 1);
    // ---- local distance update + thread-local argmax (float compare) ----
    float bestd = -1.0f; int bestk = 0;
#pragma unroll
    for (int k = 0; k < FPS_PPT; k++) {
      // exactly match reference: nd = sqrt(dx*dx + dy*dy), no fma contraction
      float dx = __fsub_rn(px[k], cx), dy = __fsub_rn(py[k], cy);
      float d2 = __fadd_rn(__fmul_rn(dx, dx), __fmul_rn(dy, dy));
      float nd = __fsqrt_rn(d2);              // correctly-rounded sqrt
      float dm = fminf(dist[k], nd);
      dist[k] = dm;
      if (dm > bestd) { bestd = dm; bestk = k; }   // strict > : lowest k on tie
    }
    const int bg = gbase + bestk * (FPS_NB * FPS_NT);
    unsigned long long key = ((unsigned long long)__float_as_uint(bestd) << 32)
                           | ((unsigned long long)tag << 17)
                           | (unsigned)(N_PTS - 1 - bg);
    // ---- wave max-reduce (u64 key only) ----
#pragma unroll
    for (int off = 32; off > 0; off >>= 1) {
      unsigned long long ok = __shfl_down(key, off);
      if (ok > key) key = ok;
    }
    if (lane == 0) lred[wid] = key;
    __syncthreads();
    if (wid == 0) {
      key = (lane < FPS_NW) ? lred[lane] : 0ull;
#pragma unroll
      for (int off = FPS_NW / 2; off > 0; off >>= 1) {
        unsigned long long ok = __shfl_down(key, off);
        if (ok > key) key = ok;
      }
      // double-buffered slots by step parity: a block only writes step s+2
      // after consuming all step-s+1 slots (store value is data-dependent on
      // those loads), and every s+1 writer consumed all step-s slots first.
      unsigned long long* sl = slots + (size_t)(s & 1) * FPS_NB * SLOT_STRIDE;
      if (lane == 0) {
        unsigned long long* ad = &sl[(size_t)b * SLOT_STRIDE];
        asm volatile("global_store_dwordx2 %0, %1, off sc0 sc1"
                     :: "v"(ad), "v"(key) : "memory");
      }
      unsigned long long gk = 0ull;
      if (lane < FPS_NB) {
        unsigned long long* ad = &sl[(size_t)lane * SLOT_STRIDE];
        unsigned long long v;
        for (;;) {
          asm volatile("global_load_dwordx2 %0, %1, off sc0 sc1\n\ts_waitcnt vmcnt(0)"
                       : "=v"(v) : "v"(ad) : "memory");
          if (((unsigned)v >> 17) == tag) break;
          __builtin_amdgcn_s_sleep(1);   // ~64cy backoff: don't flood the fabric
        }
        gk = v;
      }
#pragma unroll
      for (int off = FPS_NB / 2; off > 0; off >>= 1) {
        unsigned long long ok = __shfl_down(gk, off);
        if (ok > gk) gk = ok;
      }
      if (lane == 0) {
        int idx = N_PTS - 1 - (int)(gk & 0x1FFFFull);
        float gx = pts[2 * idx], gy = pts[2 * idx + 1];   // L2-resident
        s_cx = gx; s_cy = gy;
        if (b == 0) {
          cents[2 * (s + 1)] = gx; cents[2 * (s + 1) + 1] = gy;
          outc[2 * (s + 1)] = gx;  outc[2 * (s + 1) + 1] = gy;
        }
      }
    }
    __syncthreads();
    cx = s_cx; cy = s_cy;
  }
}

// ---------------- nearest-centroid assignment ----------------
__global__ __launch_bounds__(256)
void assign_kernel(const float* __restrict__ pts, const float* __restrict__ cents,
                   int* __restrict__ assign) {
  __shared__ float scx[M_CENT], scy[M_CENT], sc2[M_CENT];
  const int t = threadIdx.x;
  for (int i = t; i < M_CENT; i += 256) {
    float x = cents[2 * i], y = cents[2 * i + 1];
    scx[i] = x; scy[i] = y;
    sc2[i] = __fadd_rn(__fmul_rn(x, x), __fmul_rn(y, y));
  }
  __syncthreads();
  const int n = blockIdx.x * 256 + t;
  float x = pts[2 * n], y = pts[2 * n + 1];
  float p2 = __fadd_rn(__fmul_rn(x, x), __fmul_rn(y, y));
  float best = __builtin_inff(); int bm = 0;
  for (int m = 0; m < M_CENT; m++) {
    // reference formula: (p2 + c2) - 2*(p.c), no fma
    float dot = __fadd_rn(__fmul_rn(x, scx[m]), __fmul_rn(y, scy[m]));
    float d2 = __fsub_rn(__fadd_rn(p2, sc2[m]), __fmul_rn(2.0f, dot));
    if (d2 < best) { best = d2; bm = m; }   // strict < : first-min tie-break
  }
  assign[n] = bm;
}

// ---------------- chunk histogram + intra-chunk stable rank ----------------
__global__ __launch_bounds__(256)
void hist_kernel(const int* __restrict__ assign, unsigned* __restrict__ gcounts,
                 unsigned char* __restrict__ ranks) {
  __shared__ unsigned hist[M_CENT];
  __shared__ int sa[256];
  const int t = threadIdx.x, c = blockIdx.x;
  for (int i = t; i < M_CENT; i += 256) hist[i] = 0u;
  __syncthreads();
  const int n = c * 256 + t;
  const int m = assign[n];
  sa[t] = m;
  atomicAdd(&hist[m], 1u);
  __syncthreads();
  int r = 0;
  for (int j = 0; j < t; j++) r += (sa[j] == m);   // broadcast LDS reads
  ranks[n] = (unsigned char)r;
  for (int i = t; i < M_CENT; i += 256) gcounts[(size_t)c * M_CENT + i] = hist[i];
}

// ---------------- per-centroid exclusive scan over chunks ----------------
__global__ __launch_bounds__(256)
void scan_kernel(unsigned* __restrict__ gcounts, unsigned* __restrict__ counts) {
  const int m = blockIdx.x * 256 + threadIdx.x;   // 8 blocks -> 2048 centroids
  unsigned run = 0;
  for (int ch = 0; ch < NCHUNK; ch++) {
    unsigned v = gcounts[(size_t)ch * M_CENT + m];
    gcounts[(size_t)ch * M_CENT + m] = run;
    run += v;
  }
  counts[m] = run;
}

// ---------------- scatter first-32 (lowest-index) per centroid ----------------
__global__ __launch_bounds__(256)
void scatter_kernel(const int* __restrict__ assign, const unsigned char* __restrict__ ranks,
                    const unsigned* __restrict__ gexcl, int* __restrict__ sel) {
  const int n = blockIdx.x * 256 + threadIdx.x;
  const int m = assign[n];
  unsigned pos = gexcl[(size_t)blockIdx.x * M_CENT + m] + (unsigned)ranks[n];
  if (pos < K_GRP) sel[m * K_GRP + pos] = n;
}

// ---------------- gather + HF encoding ----------------
__global__ __launch_bounds__(256)
void encode_kernel(const float* __restrict__ pts, const float* __restrict__ cents,
                   const int* __restrict__ sel, const unsigned* __restrict__ counts,
                   float* __restrict__ enc) {
  const int tid = blockIdx.x * 256 + threadIdx.x;   // 0..65535
  const int m = tid >> 5, k = tid & 31;
  const unsigned cnt = counts[m];
  const float cx = cents[2 * m], cy = cents[2 * m + 1];
  float rx, ry;
  if (cnt == 0u) {
    if (k == 0) { rx = 0.f; ry = 0.f; }             // slot0 = centroid -> rel 0
    else        { rx = 0.f - cx; ry = 0.f - cy; }   // others grouped=0 -> rel=-c
  } else {
    int kk = ((unsigned)k < cnt) ? k : (int)cnt - 1;  // pad with last assigned
    int n = sel[m * K_GRP + kk];
    rx = __fsub_rn(pts[2 * n], cx);
    ry = __fsub_rn(pts[2 * n + 1], cy);
  }
  float row[40];
  float fr = 3.14159265358979323846f;   // rounds to float(pi); doubling is exact
#pragma unroll
  for (int f = 0; f < 10; f++) {
    float ax = __fmul_rn(rx, fr), ay = __fmul_rn(ry, fr);
    float sx, cxs, sy, cys;
    sincosf(ax, &sx, &cxs);
    sincosf(ay, &sy, &cys);
    row[f * 4 + 0] = sx; row[f * 4 + 1] = cxs;
    row[f * 4 + 2] = sy; row[f * 4 + 3] = cys;
    fr = fr * 2.0f;
  }
  float4* dst = (float4*)(enc + (size_t)tid * 40);
#pragma unroll
  for (int i = 0; i < 10; i++)
    dst[i] = make_float4(row[4 * i], row[4 * i + 1], row[4 * i + 2], row[4 * i + 3]);
}

// ---------------- zero the stat accumulators (ws is poisoned) ----------------
__global__ void zero_stats(float* __restrict__ s1, float* __restrict__ s2) {
  int t = threadIdx.x;
  if (t < 128) s1[t] = 0.f;
  s2[t] = 0.f;   // 256 threads cover 256
}

// ---------------- GEMM1 + BN1 stats (Z1 discarded) ----------------
__global__ __launch_bounds__(256)
void gemm1_stats(const float* __restrict__ enc, const float* __restrict__ W1,
                 const float* __restrict__ b1, float* __restrict__ stats1) {
  __shared__ float w1t[64 * 40];   // transposed: w1t[c*40+k]
  __shared__ float b1s[64];
  __shared__ float acc[128];
  const int t = threadIdx.x;
  for (int i = t; i < 2560; i += 256) { int c = i / 40, k = i % 40; w1t[i] = W1[k * 64 + c]; }
  if (t < 64) b1s[t] = b1[t];
  if (t < 128) acc[t] = 0.f;
  __syncthreads();
  const int row = blockIdx.x * 256 + t;
  const int lane = t & 63;
  float x[40];
  const float4* er = (const float4*)(enc + (size_t)row * 40);
#pragma unroll
  for (int i = 0; i < 10; i++) { float4 v = er[i]; x[4*i]=v.x; x[4*i+1]=v.y; x[4*i+2]=v.z; x[4*i+3]=v.w; }
  for (int c = 0; c < 64; c++) {
    float z = b1s[c];
    const float4* wc = (const float4*)(w1t + c * 40);
#pragma unroll
    for (int q = 0; q < 10; q++) {
      float4 w = wc[q];
      z += x[4*q]*w.x + x[4*q+1]*w.y + x[4*q+2]*w.z + x[4*q+3]*w.w;
    }
    float s = z, s2 = z * z;
#pragma unroll
    for (int off = 32; off > 0; off >>= 1) { s += __shfl_down(s, off); s2 += __shfl_down(s2, off); }
    if (lane == 0) { atomicAdd(&acc[c], s); atomicAdd(&acc[64 + c], s2); }
  }
  __syncthreads();
  if (t < 128) atomicAdd(&stats1[t], acc[t]);
}

// ---------------- finalize BN params: a = g*rsqrt(var+eps), b' = be - a*mu ----
__global__ void finalize_bn(const float* __restrict__ stats, const float* __restrict__ g,
                            const float* __restrict__ be, float* __restrict__ ab, int C) {
  int c = threadIdx.x;
  if (c < C) {
    const float invN = 1.0f / (float)NROWS;
    float mu = stats[c] * invN;
    float var = stats[C + c] * invN - mu * mu;
    float a = g[c] * rsqrtf(var + BN_EPS);
    ab[c] = a; ab[C + c] = be[c] - a * mu;
  }
}

// ---------------- GEMM1->BN1->relu->GEMM2 + BN2 stats (Z2 discarded) --------
__global__ __launch_bounds__(256)
void gemm2_stats(const float* __restrict__ enc, const float* __restrict__ W1,
                 const float* __restrict__ b1, const float* __restrict__ ab1,
                 const float* __restrict__ W2, const float* __restrict__ b2,
                 float* __restrict__ stats2) {
  __shared__ float w1t[64 * 40];    // [c][k]
  __shared__ float w2t[128 * 64];   // [c2][j]
  __shared__ float b1s[64], b2s[128], ab1s[128];
  __shared__ float acc[256];
  const int t = threadIdx.x;
  for (int i = t; i < 2560; i += 256) { int c = i / 40, k = i % 40; w1t[i] = W1[k * 64 + c]; }
  for (int i = t; i < 8192; i += 256) { int c = i / 64, j = i % 64; w2t[i] = W2[j * 128 + c]; }
  if (t < 64) b1s[t] = b1[t];
  if (t < 128) { b2s[t] = b2[t]; ab1s[t] = ab1[t]; }
  if (t < 64) ab1s[64 + t] = ab1[64 + t];
  acc[t] = 0.f;
  __syncthreads();
  const int row = blockIdx.x * 256 + t;
  const int lane = t & 63;
  float x[40];
  const float4* er = (const float4*)(enc + (size_t)row * 40);
#pragma unroll
  for (int i = 0; i < 10; i++) { float4 v = er[i]; x[4*i]=v.x; x[4*i+1]=v.y; x[4*i+2]=v.z; x[4*i+3]=v.w; }
  float h[64];
  for (int c = 0; c < 64; c++) {
    float z = b1s[c];
    const float4* wc = (const float4*)(w1t + c * 40);
#pragma unroll
    for (int q = 0; q < 10; q++) {
      float4 w = wc[q];
      z += x[4*q]*w.x + x[4*q+1]*w.y + x[4*q+2]*w.z + x[4*q+3]*w.w;
    }
    h[c] = fmaxf(fmaf(ab1s[c], z, ab1s[64 + c]), 0.f);
  }
  for (int c = 0; c < 128; c++) {
    float z = b2s[c];
    const float4* wc = (const float4*)(w2t + c * 64);
#pragma unroll
    for (int q = 0; q < 16; q++) {
      float4 w = wc[q];
      z += h[4*q]*w.x + h[4*q+1]*w.y + h[4*q+2]*w.z + h[4*q+3]*w.w;
    }
    float s = z, s2 = z * z;
#pragma unroll
    for (int off = 32; off > 0; off >>= 1) { s += __shfl_down(s, off); s2 += __shfl_down(s2, off); }
    if (lane == 0) { atomicAdd(&acc[c], s); atomicAdd(&acc[128 + c], s2); }
  }
  __syncthreads();
  atomicAdd(&stats2[t], acc[t]);
}

// ---------------- full MLP + group max ----------------
__global__ __launch_bounds__(256)
void final_kernel(const float* __restrict__ enc, const float* __restrict__ W1,
                  const float* __restrict__ b1, const float* __restrict__ ab1,
                  const float* __restrict__ W2, const float* __restrict__ b2,
                  const float* __restrict__ ab2, const float* __restrict__ W3,
                  const float* __restrict__ b3, float* __restrict__ out_feat) {
  __shared__ float w1t[64 * 40];
  __shared__ float w2t[128 * 64];
  __shared__ float w3s[128 * 16];
  __shared__ float b1s[64], b2s[128], b3s[16], ab1s[128], ab2s[256];
  __shared__ float srow[256][16];
  const int t = threadIdx.x;
  for (int i = t; i < 2560; i += 256) { int c = i / 40, k = i % 40; w1t[i] = W1[k * 64 + c]; }
  for (int i = t; i < 8192; i += 256) { int c = i / 64, j = i % 64; w2t[i] = W2[j * 128 + c]; }
  for (int i = t; i < 2048; i += 256) w3s[i] = W3[i];
  if (t < 64) b1s[t] = b1[t];
  if (t < 128) { b2s[t] = b2[t]; ab1s[t] = ab1[t]; }
  if (t < 64) ab1s[64 + t] = ab1[64 + t];
  ab2s[t] = ab2[t];
  if (t < 16) b3s[t] = b3[t];
  __syncthreads();
  const int row = blockIdx.x * 256 + t;
  float x[40];
  const float4* er = (const float4*)(enc + (size_t)row * 40);
#pragma unroll
  for (int i = 0; i < 10; i++) { float4 v = er[i]; x[4*i]=v.x; x[4*i+1]=v.y; x[4*i+2]=v.z; x[4*i+3]=v.w; }
  float h[64];
  for (int c = 0; c < 64; c++) {
    float z = b1s[c];
    const float4* wc = (const float4*)(w1t + c * 40);
#pragma unroll
    for (int q = 0; q < 10; q++) {
      float4 w = wc[q];
      z += x[4*q]*w.x + x[4*q+1]*w.y + x[4*q+2]*w.z + x[4*q+3]*w.w;
    }
    h[c] = fmaxf(fmaf(ab1s[c], z, ab1s[64 + c]), 0.f);
  }
  float acc[16];
#pragma unroll
  for (int o = 0; o < 16; o++) acc[o] = b3s[o];
  for (int j = 0; j < 128; j++) {
    float z = b2s[j];
    const float4* wc = (const float4*)(w2t + j * 64);
#pragma unroll
    for (int q = 0; q < 16; q++) {
      float4 w = wc[q];
      z += h[4*q]*w.x + h[4*q+1]*w.y + h[4*q+2]*w.z + h[4*q+3]*w.w;
    }
    float h2 = fmaxf(fmaf(ab2s[j], z, ab2s[128 + j]), 0.f);
    const float4* w3r = (const float4*)(w3s + j * 16);
#pragma unroll
    for (int q = 0; q < 4; q++) {
      float4 w = w3r[q];
      acc[4*q] += h2 * w.x; acc[4*q+1] += h2 * w.y; acc[4*q+2] += h2 * w.z; acc[4*q+3] += h2 * w.w;
    }
  }
#pragma unroll
  for (int o = 0; o < 16; o++) srow[t][o] = acc[o];
  __syncthreads();
  if (t < 128) {
    const int g = t >> 4, c = t & 15;
    float mx = srow[g * 32][c];
#pragma unroll
    for (int r = 1; r < 32; r++) mx = fmaxf(mx, srow[g * 32 + r][c]);
    out_feat[(size_t)(blockIdx.x * 8 + g) * 16 + c] = mx;
  }
}

// ---------------- host launcher ----------------
extern "C" void kernel_launch(void* const* d_in, const int* in_sizes, int n_in,
                              void* d_out, int out_size, void* d_ws, size_t ws_size,
                              hipStream_t stream) {
  const float* pts = (const float*)d_in[0];
  const float* W1 = (const float*)d_in[1];  const float* b1 = (const float*)d_in[2];
  const float* g1 = (const float*)d_in[3];  const float* be1 = (const float*)d_in[4];
  const float* W2 = (const float*)d_in[5];  const float* b2 = (const float*)d_in[6];
  const float* g2 = (const float*)d_in[7];  const float* be2 = (const float*)d_in[8];
  const float* W3 = (const float*)d_in[9];  const float* b3 = (const float*)d_in[10];
  float* out = (float*)d_out;   // [2048*16 features | 2048*2 centroids]

  char* w = (char*)d_ws;
  auto carve = [&](size_t bytes) -> char* {
    char* p = w;
    w += (bytes + 255) & ~(size_t)255;
    return p;
  };
  unsigned long long* slots = (unsigned long long*)carve((size_t)2 * FPS_NB * SLOT_STRIDE * 8);
  float*    cents  = (float*)carve((size_t)M_CENT * 2 * 4);
  int*      assign = (int*)carve((size_t)N_PTS * 4);
  unsigned char* ranks = (unsigned char*)carve((size_t)N_PTS);
  unsigned* gcounts = (unsigned*)carve((size_t)NCHUNK * M_CENT * 4);
  unsigned* counts  = (unsigned*)carve((size_t)M_CENT * 4);
  int*      sel     = (int*)carve((size_t)M_CENT * K_GRP * 4);
  float*    enc     = (float*)carve((size_t)NROWS * 40 * 4);
  float*    stats1  = (float*)carve(128 * 4);
  float*    stats2  = (float*)carve(256 * 4);
  float*    ab1     = (float*)carve(128 * 4);
  float*    ab2     = (float*)carve(256 * 4);

  float* out_feat = out;
  float* out_cent = out + (size_t)M_CENT * 16;

  hipLaunchKernelGGL(zero_stats, dim3(1), dim3(256), 0, stream, stats1, stats2);
  hipLaunchKernelGGL(fps_kernel, dim3(FPS_NB), dim3(FPS_NT), 0, stream,
                     pts, cents, out_cent, slots);
  hipLaunchKernelGGL(assign_kernel, dim3(N_PTS / 256), dim3(256), 0, stream,
                     pts, cents, assign);
  hipLaunchKernelGGL(hist_kernel, dim3(NCHUNK), dim3(256), 0, stream,
                     assign, gcounts, ranks);
  hipLaunchKernelGGL(scan_kernel, dim3(M_CENT / 256), dim3(256), 0, stream,
                     gcounts, counts);
  hipLaunchKernelGGL(scatter_kernel, dim3(NCHUNK), dim3(256), 0, stream,
                     assign, ranks, gcounts, sel);
  hipLaunchKernelGGL(encode_kernel, dim3(NROWS / 256), dim3(256), 0, stream,
                     pts, cents, sel, counts, enc);
  hipLaunchKernelGGL(gemm1_stats, dim3(NROWS / 256), dim3(256), 0, stream,
                     enc, W1, b1, stats1);
  hipLaunchKernelGGL(finalize_bn, dim3(1), dim3(64), 0, stream, stats1, g1, be1, ab1, 64);
  hipLaunchKernelGGL(gemm2_stats, dim3(NROWS / 256), dim3(256), 0, stream,
                     enc, W1, b1, ab1, W2, b2, stats2);
  hipLaunchKernelGGL(finalize_bn, dim3(1), dim3(128), 0, stream, stats2, g2, be2, ab2, 128);
  hipLaunchKernelGGL(final_kernel, dim3(NROWS / 256), dim3(256), 0, stream,
                     enc, W1, b1, ab1, W2, b2, ab2, W3, b3, out_feat);
}